// Round 1
// baseline (28407.825 us; speedup 1.0000x reference)
//
#include <hip/hip_runtime.h>

typedef float v2f __attribute__((ext_vector_type(2)));

#define T_STEPS 100000
#define UDIM 7
#define NCHUNK 1562   /* full 64-step chunks */
#define TAIL 32       /* 100000 - 1562*64 */
#define ZSTR 68       /* zhist row stride (floats) */
#define ZH (64 * ZSTR)
#define UROWS 65      /* 64 steps + duplicated row0 of next chunk */
#define UAB (UROWS * 64)

#if __has_builtin(__builtin_amdgcn_permlane32_swap) && __has_builtin(__builtin_amdgcn_permlane16_swap)
#define HAS_PLSWAP 1
#else
#define HAS_PLSWAP 0
#endif

/* weights pre-scaled by exactly 2.0: tanh(x) = 1 - 2/(exp(2x)+1), arg arrives as 2x */
__device__ __forceinline__ float tanh_pre(float xs) {
    float e = __expf(xs);
    return 1.0f - 2.0f * __builtin_amdgcn_rcpf(e + 1.0f);
}

__device__ __forceinline__ float readlane_f(float v, int l) {
    return __int_as_float(__builtin_amdgcn_readlane(__float_as_int(v), l));
}

template <int CTRL>
__device__ __forceinline__ float dpp_f(float v) {
    return __int_as_float(__builtin_amdgcn_update_dpp(
        0, __float_as_int(v), CTRL, 0xF, 0xF, true));
}

template <int M> struct IC { static constexpr int v = M; };

__global__ __launch_bounds__(128) __attribute__((amdgpu_waves_per_eu(1, 1)))
void node_scan(const float* __restrict__ U,
               const float* __restrict__ W1, const float* __restrict__ b1,
               const float* __restrict__ W2, const float* __restrict__ b2,
               const float* __restrict__ W3, const float* __restrict__ b3,
               const float* __restrict__ wd, const float* __restrict__ bd,
               const float* __restrict__ wt, const float* __restrict__ bt,
               const float* __restrict__ wc, const float* __restrict__ bc,
               const float* __restrict__ h0,
               float* __restrict__ out)
{
    const int tid  = threadIdx.x;
    const int wv   = tid >> 6;               // 0 = compute wave, 1 = service wave
    const int lane = tid & 63;
    const float dt = (float)(5.0 / 60.0);

    __shared__ __align__(16) float zbuf[64];          // m3od staging / vacc scatter
    __shared__ __align__(16) float ubuf[3 * 512];     // u chunks (wave1-only)
    __shared__ __align__(16) float zhist[2 * ZH];     // z2 history, double-buffered
    __shared__ __align__(16) float cbuf[3 * 64];      // readout functionals (wave1)
    __shared__ __align__(16) float uab[2 * UAB];      // uacc tables, double-buffered
    __shared__ __align__(16) float Msh[64 * 64];      // M staging (init only)
    __shared__ int flg[4];                            // 0=w0 done,1=uacc ready,2=batch done

    if (tid == 0) { flg[0] = 0; flg[1] = 0; flg[2] = 0; }

    // persisted across the pre/post-sync wave0 sections
    int dlt = 1, mode = 1;
    float A = 0.f, m3od = 0.f;
    // wave1 regs
    v2f W1up[3]; float W1u6 = 0.f, b1l = 0.f;
    float rbD = 0.f, rbT = 0.f, rbC = 0.f, rchD = 0.f, rchT = 0.f, rchC = 0.f;

    if (wv == 0) {
        const int cl = lane & 15;
        // --- DPP rotation-direction probe (absorbed into weight indexing) ---
        {
            float pd = dpp_f<0x121>((float)cl);      // row_ror:1
            dlt = ((int)pd - cl) & 15;               // per-ror1 source-lane delta (1 or 15)
        }
        // --- permlane-swap semantics probe (expected: partition semantics) ---
#if HAS_PLSWAP
        {
            auto rp = __builtin_amdgcn_permlane32_swap(lane, 1000 + lane, false, false);
            auto rq = __builtin_amdgcn_permlane16_swap(lane, 1000 + lane, false, false);
            bool ok =
                (int)rp[0] == ((lane & 32) ? 1000 + lane - 32 : lane) &&
                (int)rp[1] == ((lane & 32) ? 1000 + lane : lane + 32) &&
                (int)rq[0] == ((lane & 16) ? 1000 + lane - 16 : lane) &&
                (int)rq[1] == ((lane & 16) ? 1000 + lane : lane + 16);
            if (__ballot(ok) == ~0ull) mode = 0;
        }
#endif
        // --- per-lane scaled W1h row; build M = (2*W1h) @ W3 into LDS ---
        float w1h[16];
#pragma unroll
        for (int j = 0; j < 16; ++j) w1h[j] = 2.0f * W1[lane * 23 + j];
        for (int cc = 0; cc < 64; ++cc) {
            float acc = 0.f;
#pragma unroll
            for (int k = 0; k < 16; ++k) acc = fmaf(w1h[k], W3[k * 64 + cc], acc);
            Msh[lane * 64 + cc] = acc;
        }
#pragma unroll
        for (int k = 0; k < 16; ++k) {
            m3od = fmaf(w1h[k], b3[k], m3od);   // scaled w1h . b3 (own output row)
            A    = fmaf(w1h[k], h0[k], A);      // scaled initial A
        }
        zbuf[lane] = m3od;                       // share m3od across lanes (mode-0 gather)
    } else {
        // u-part weights for this lane's row (scaled by 2 for exp-folding)
#pragma unroll
        for (int j = 0; j < 3; ++j) {
            W1up[j].x = 2.0f * W1[lane * 23 + 16 + 2 * j];
            W1up[j].y = 2.0f * W1[lane * 23 + 17 + 2 * j];
        }
        W1u6 = 2.0f * W1[lane * 23 + 22];
        b1l = 2.0f * b1[lane];
        // readout functionals c = W3^T w -> LDS (UNSCALED)
        float cd = 0.f, ct = 0.f, ccv = 0.f;
        for (int k = 0; k < 16; ++k) {
            const float w3v = W3[k * 64 + lane];
            cd = fmaf(wd[k], w3v, cd);
            ct = fmaf(wt[k], w3v, ct);
            ccv = fmaf(wc[k], w3v, ccv);
        }
        cbuf[lane] = cd; cbuf[64 + lane] = ct; cbuf[128 + lane] = ccv;
        rchD = bd[0]; rchT = bt[0]; rchC = bc[0];
        for (int k = 0; k < 16; ++k) {
            rbD = fmaf(wd[k], b3[k], rbD);  rchD = fmaf(wd[k], h0[k], rchD);
            rbT = fmaf(wt[k], b3[k], rbT);  rchT = fmaf(wt[k], h0[k], rchT);
            rbC = fmaf(wc[k], b3[k], rbC);  rchC = fmaf(wc[k], h0[k], rchC);
        }
        rbD *= dt; rbT *= dt; rbC *= dt;
        // stage u chunks 0,1,2
#pragma unroll
        for (int c = 0; c < 3; ++c) {
            const int base = c * 448, dst = c * 512;
#pragma unroll
            for (int rr = 0; rr < UDIM; ++rr) {
                int flat = rr * 64 + lane;
                int s = flat / 7, cc2 = flat % 7;
                ubuf[dst + s * 8 + cc2] = U[base + flat];
            }
            ubuf[dst + lane * 8 + 7] = 0.f;
        }
    }
    __syncthreads();

    if (wv == 0) {
        const int r  = lane >> 4;   // DPP row (owns z indices [16r,16r+16))
        const int cl = lane & 15;   // column within row

        auto runw0 = [&](auto MC) {
            constexpr int MODE = decltype(MC)::v;
            // ---- preload rotation-ordered weight fragments ----
            // slot d covers output o = 16*d+cl (MODE 0) or 16*(r^d)+cl (MODE 1),
            // k walks this lane's row in the probed DPP rotation order.
            v2f W2f[4][8], Mf[4][8];
            float b2v[4], m3v[4];
            {
                int offA = 0, offB = (15 * dlt) & 15;
#pragma unroll
                for (int s = 0; s < 8; ++s) {
                    const int kA = (r << 4) | ((cl + offA) & 15);
                    const int kB = (r << 4) | ((cl + offB) & 15);
#pragma unroll
                    for (int d = 0; d < 4; ++d) {
                        const int o = ((MODE ? (r ^ d) : d) << 4) | cl;
                        W2f[d][s] = (v2f){2.0f * W2[o * 64 + kA], 2.0f * W2[o * 64 + kB]};
                        Mf[d][s]  = (v2f){Msh[o * 64 + kA], Msh[o * 64 + kB]};
                    }
                    offA = (offA + 2 * dlt) & 15;
                    offB = (offB + 2 * dlt) & 15;
                }
#pragma unroll
                for (int d = 0; d < 4; ++d) {
                    if (MODE == 0) {  // bias counted once: at row-0 lanes
                        b2v[d] = (r == 0) ? 2.0f * b2[(d << 4) | cl] : 0.f;
                        m3v[d] = (r == 0) ? zbuf[(d << 4) | cl] : 0.f;
                    } else {          // XOR map: own output lives in slot 0
                        b2v[d] = (d == 0) ? 2.0f * b2[lane] : 0.f;
                        m3v[d] = (d == 0) ? m3od : 0.f;
                    }
                }
            }

            // cross-row reduction of the 4 per-row partials -> own output per lane
            auto combine = [&](v2f a0, v2f a1, v2f a2, v2f a3) -> float {
                float P0 = a0.x + a0.y, P1 = a1.x + a1.y;
                float P2 = a2.x + a2.y, P3 = a3.x + a3.y;
#if HAS_PLSWAP
                if constexpr (MODE == 0) {
                    auto rA = __builtin_amdgcn_permlane32_swap(__float_as_int(P0), __float_as_int(P2), false, false);
                    auto rB = __builtin_amdgcn_permlane32_swap(__float_as_int(P1), __float_as_int(P3), false, false);
                    float U02 = __int_as_float((int)rA[0]) + __int_as_float((int)rA[1]); // lo:S0 hi:S2
                    float U13 = __int_as_float((int)rB[0]) + __int_as_float((int)rB[1]); // lo:S1 hi:S3
                    auto sA = __builtin_amdgcn_permlane16_swap(__float_as_int(U02), __float_as_int(U02), false, false);
                    auto sB = __builtin_amdgcn_permlane16_swap(__float_as_int(U13), __float_as_int(U13), false, false);
                    float V02 = __int_as_float((int)sA[0]) + __int_as_float((int)sA[1]); // rows01:T0 rows23:T2
                    float V13 = __int_as_float((int)sB[0]) + __int_as_float((int)sB[1]); // rows01:T1 rows23:T3
                    return (lane & 16) ? V13 : V02;
                }
#endif
                {   // fallback: known-semantics LDS-crossbar butterfly (XOR slot map)
                    float q0 = P0 + __int_as_float(__builtin_amdgcn_ds_bpermute((lane ^ 32) << 2, __float_as_int(P2)));
                    float q1 = P1 + __int_as_float(__builtin_amdgcn_ds_bpermute((lane ^ 32) << 2, __float_as_int(P3)));
                    return q0 + __int_as_float(__builtin_amdgcn_ds_swizzle(__float_as_int(q1), 0x401F));
                }
            };

            while (__hip_atomic_load(&flg[1], __ATOMIC_ACQUIRE,
                                     __HIP_MEMORY_SCOPE_WORKGROUP) < 1)
                __builtin_amdgcn_s_sleep(1);
            float uacc = uab[lane];                        // chunk0 row0

            auto step = [&](int li, int ub4, int zb4) {
                const float z1 = tanh_pre(A + uacc);
                const float uacc_next = uab[ub4 + (li + 1) * 64 + lane];
                // rotating pair: {z[k_A], z[k_B]} sweeping this lane's row
                v2f zp; zp.x = z1; zp.y = dpp_f<0x12F>(z1);   // ror:15 partner chain
                v2f a0 = {b2v[0], 0.f}, a1 = {b2v[1], 0.f};
                v2f a2 = {b2v[2], 0.f}, a3 = {b2v[3], 0.f};
#pragma unroll
                for (int s = 0; s < 8; ++s) {
                    a0 = __builtin_elementwise_fma(W2f[0][s], zp, a0);
                    a1 = __builtin_elementwise_fma(W2f[1][s], zp, a1);
                    a2 = __builtin_elementwise_fma(W2f[2][s], zp, a2);
                    a3 = __builtin_elementwise_fma(W2f[3][s], zp, a3);
                    if (s < 7) { zp.x = dpp_f<0x122>(zp.x); zp.y = dpp_f<0x122>(zp.y); }
                }
                const float z2 = tanh_pre(combine(a0, a1, a2, a3));
                zhist[zb4 + li * ZSTR + lane] = z2;           // write-only for wave0 now
                v2f wp; wp.x = z2; wp.y = dpp_f<0x12F>(z2);
                v2f m0 = {m3v[0], 0.f}, m1 = {m3v[1], 0.f};
                v2f m2 = {m3v[2], 0.f}, m3r = {m3v[3], 0.f};
#pragma unroll
                for (int s = 0; s < 8; ++s) {
                    m0  = __builtin_elementwise_fma(Mf[0][s], wp, m0);
                    m1  = __builtin_elementwise_fma(Mf[1][s], wp, m1);
                    m2  = __builtin_elementwise_fma(Mf[2][s], wp, m2);
                    m3r = __builtin_elementwise_fma(Mf[3][s], wp, m3r);
                    if (s < 7) { wp.x = dpp_f<0x122>(wp.x); wp.y = dpp_f<0x122>(wp.y); }
                }
                A = fmaf(dt, combine(m0, m1, m2, m3r), A);
                uacc = uacc_next;
            };

            for (int cb = 0; cb <= NCHUNK; ++cb) {
                while (__hip_atomic_load(&flg[1], __ATOMIC_ACQUIRE,
                                         __HIP_MEMORY_SCOPE_WORKGROUP) < cb + 1)
                    __builtin_amdgcn_s_sleep(1);
                while (__hip_atomic_load(&flg[2], __ATOMIC_ACQUIRE,
                                         __HIP_MEMORY_SCOPE_WORKGROUP) < cb - 1)
                    __builtin_amdgcn_s_sleep(1);
                const int zb4 = (cb & 1) * ZH;
                const int ub4 = (cb & 1) * UAB;
                if (cb < NCHUNK) {
#pragma unroll 4
                    for (int li = 0; li < 64; ++li) step(li, ub4, zb4);
                } else {
#pragma unroll 4
                    for (int li = 0; li < TAIL; ++li) step(li, ub4, zb4);
                }
                __hip_atomic_store(&flg[0], cb + 1, __ATOMIC_RELEASE,
                                   __HIP_MEMORY_SCOPE_WORKGROUP);
            }
        };
        if (mode == 0) runw0(IC<0>{}); else runw0(IC<1>{});
    } else {
        // =================== wave 1: staging + uacc + readouts ==============
        float vacc = 0.f;   // per-component z2 sum (for h(T))

        auto uacc_chunk = [&](int c) {
            const int par = (c & 1) * UAB;
            const int src = (c % 3) * 512;
            const int nxt = ((c + 1) % 3) * 512;
            for (int li = 0; li < UROWS; ++li) {
                const int uo = (li < 64) ? src + li * 8 : nxt;
                float4 ua = *(const float4*)&ubuf[uo];
                float4 ub = *(const float4*)&ubuf[uo + 4];
                v2f uv = __builtin_elementwise_fma(W1up[0], (v2f){ua.x, ua.y}, (v2f){0.f, 0.f});
                uv = __builtin_elementwise_fma(W1up[1], (v2f){ua.z, ua.w}, uv);
                uv = __builtin_elementwise_fma(W1up[2], (v2f){ub.x, ub.y}, uv);
                uab[par + li * 64 + lane] = uv.x + uv.y + fmaf(W1u6, ub.z, b1l);
            }
        };
        uacc_chunk(0);
        uacc_chunk(1);
        __hip_atomic_store(&flg[1], 2, __ATOMIC_RELEASE,
                           __HIP_MEMORY_SCOPE_WORKGROUP);

        for (int cb = 0; cb <= NCHUNK; ++cb) {
            while (__hip_atomic_load(&flg[0], __ATOMIC_ACQUIRE,
                                     __HIP_MEMORY_SCOPE_WORKGROUP) < cb + 1)
                __builtin_amdgcn_s_sleep(8);
            if (cb + 3 <= NCHUNK) {
                const int dst = ((cb + 3) % 3) * 512;
                const int base = (cb + 3) * 448;
#pragma unroll
                for (int rr = 0; rr < UDIM; ++rr) {
                    int idx = base + rr * 64 + lane;
                    if (idx > T_STEPS * UDIM - 1) idx = T_STEPS * UDIM - 1;
                    const float val = U[idx];
                    int flat = rr * 64 + lane;
                    int s = flat / 7, c = flat % 7;
                    ubuf[dst + s * 8 + c] = val;
                }
            }
            if (cb + 2 <= NCHUNK) {
                uacc_chunk(cb + 2);
                __hip_atomic_store(&flg[1], cb + 3, __ATOMIC_RELEASE,
                                   __HIP_MEMORY_SCOPE_WORKGROUP);
            }
            // ---- batched readouts + vacc for chunk cb ----
            const int zb4 = (cb & 1) * ZH;
            const int ns = (cb == NCHUNK) ? TAIL : 64;
            float colsum = 0.f;
            for (int li = 0; li < ns; ++li) colsum += zhist[zb4 + li * ZSTR + lane];
            vacc += colsum;

            const float* zr = &zhist[zb4 + lane * ZSTR];
            v2f sd = {0.f, 0.f}, st = {0.f, 0.f}, sc = {0.f, 0.f};
#pragma unroll
            for (int qq = 0; qq < 32; ++qq) {
                v2f zv = *(const v2f*)&zr[2 * qq];
                sd = __builtin_elementwise_fma(*(const v2f*)&cbuf[2 * qq],       zv, sd);
                st = __builtin_elementwise_fma(*(const v2f*)&cbuf[64 + 2 * qq],  zv, st);
                sc = __builtin_elementwise_fma(*(const v2f*)&cbuf[128 + 2 * qq], zv, sc);
            }
            float Sd = sd.x + sd.y, St = st.x + st.y, Sc = sc.x + sc.y;
            const float oD = Sd, oT = St, oC = Sc;
#pragma unroll
            for (int dl = 1; dl < 64; dl <<= 1) {
                float ud = __shfl_up(Sd, dl, 64);
                float ut = __shfl_up(St, dl, 64);
                float uc = __shfl_up(Sc, dl, 64);
                if (lane >= dl) { Sd += ud; St += ut; Sc += uc; }
            }
            const int t = cb * 64 + lane;
            if (t < T_STEPS) {
                const float fl = (float)lane;
                out[t]               = fmaf(dt, Sd - oD, rchD) + fl * rbD;
                out[T_STEPS + t]     = fmaf(dt, St - oT, rchT) + fl * rbT;
                out[2 * T_STEPS + t] = fmaf(dt, Sc - oC, rchC) + fl * rbC;
            }
            rchD = fmaf(dt, readlane_f(Sd, 63), rchD) + 64.f * rbD;
            rchT = fmaf(dt, readlane_f(St, 63), rchT) + 64.f * rbT;
            rchC = fmaf(dt, readlane_f(Sc, 63), rchC) + 64.f * rbC;
            __hip_atomic_store(&flg[2], cb + 1, __ATOMIC_RELEASE,
                               __HIP_MEMORY_SCOPE_WORKGROUP);
        }

        // ---- h(T) = h0 + dt*W3@vacc + T*dt*b3 (wave0 fully done by now) ----
        zbuf[lane] = vacc;
        if (lane < 16) {
            const float* w3r = W3 + lane * 64;
            float h0a = 0.f, h1a = 0.f;
#pragma unroll
            for (int qq = 0; qq < 16; ++qq) {
                float4 za = *(const float4*)&zbuf[qq * 4];
                h0a = fmaf(w3r[4 * qq + 0], za.x, h0a);
                h1a = fmaf(w3r[4 * qq + 1], za.y, h1a);
                h0a = fmaf(w3r[4 * qq + 2], za.z, h0a);
                h1a = fmaf(w3r[4 * qq + 3], za.w, h1a);
            }
            out[3 * T_STEPS + lane] =
                h0[lane] + dt * (h0a + h1a) + (float)T_STEPS * dt * b3[lane];
        }
    }
}

extern "C" void kernel_launch(void* const* d_in, const int* in_sizes, int n_in,
                              void* d_out, int out_size, void* d_ws, size_t ws_size,
                              hipStream_t stream) {
    const float* U  = (const float*)d_in[0];
    const float* W1 = (const float*)d_in[1];
    const float* b1 = (const float*)d_in[2];
    const float* W2 = (const float*)d_in[3];
    const float* b2 = (const float*)d_in[4];
    const float* W3 = (const float*)d_in[5];
    const float* b3 = (const float*)d_in[6];
    const float* wd = (const float*)d_in[7];
    const float* bd = (const float*)d_in[8];
    const float* wt = (const float*)d_in[9];
    const float* bt = (const float*)d_in[10];
    const float* wc = (const float*)d_in[11];
    const float* bc = (const float*)d_in[12];
    const float* h0 = (const float*)d_in[13];
    (void)in_sizes; (void)n_in; (void)out_size; (void)d_ws; (void)ws_size;

    node_scan<<<dim3(1), dim3(128), 0, stream>>>(U, W1, b1, W2, b2, W3, b3,
                                                 wd, bd, wt, bt, wc, bc, h0,
                                                 (float*)d_out);
}